// Round 14
// baseline (13403.833 us; speedup 1.0000x reference)
//
#include <hip/hip_runtime.h>

// ---------------- problem dims ----------------
constexpr int BB = 16;       // batch
constexpr int TT = 256;      // seq len
constexpr int IN0 = 512;     // input dim (layer 0)
constexpr int HH = 1024;     // hidden
constexpr int GG = 4096;     // 4*H gates
constexpr int NLAYERS = 8;

// ---------------- ws layout (bytes) ----------------
constexpr size_t XG_OFF   = 0;                         // xg [t*16+b][4096] fp32 : 64 MB
constexpr size_t REG0_OFF = 67108864;                  // 16 MB: W_ih splits (xcv+W0 in phase 0)
constexpr size_t REG1_OFF = REG0_OFF + 16777216;       // 16 MB: hseq hi/lo (odd layers out)
constexpr size_t HE_OFF   = REG1_OFF + 16777216;       // even-layer h: 4 slots x 64 KB
constexpr size_t HO_OFF   = HE_OFF + 262144;           // odd-layer h: 4 slots x 64 KB
constexpr size_t FC1_OFF  = HO_OFF + 262144;           // 32 KB
constexpr size_t FC2_OFF  = FC1_OFF + 32768;           // 16 KB
constexpr size_t PRG_OFF  = FC2_OFF + 16384;           // prog[lwg] @ lwg*64B (8 KB)
// h exchange: packed u32 = bf16 hi | (bf16 lo with LSB := genbit) << 16.
// slot = gstep & 3; genbit = (gstep>>2)&1. Consumers spin on the DATA until
// every dword carries the expected genbit — no flags on the recurrence path.

// ---------------- scan LDS (bytes) ----------------
constexpr int BLO_B  = 69632;
constexpr int PART_F = 34816;      // float idx: [8 waves][16 r pad 17]
constexpr int SMEM_BYTES = 147968;

typedef __attribute__((ext_vector_type(8))) short bf16x8;
typedef __attribute__((ext_vector_type(4))) float f32x4;

__device__ __forceinline__ unsigned short f2bf(float f)
{
    union { float f; unsigned u; } v{f};
    unsigned r = v.u + 0x7FFFu + ((v.u >> 16) & 1u);   // RNE
    return (unsigned short)(r >> 16);
}
__device__ __forceinline__ float bf2f(unsigned short h)
{
    union { unsigned u; float f; } v{(unsigned)h << 16};
    return v.f;
}

// ---------------- split conversion: fp32 -> bf16 hi + bf16 lo ----------------
__global__ __launch_bounds__(256) void conv_split(const float* __restrict__ in,
                                                  ushort* __restrict__ oh,
                                                  ushort* __restrict__ ol, int n4)
{
    int g = blockIdx.x * blockDim.x + threadIdx.x;
    if (g >= n4) return;
    float4 f = ((const float4*)in)[g];
    ushort4 h, l;
    h.x = f2bf(f.x); l.x = f2bf(f.x - bf2f(h.x));
    h.y = f2bf(f.y); l.y = f2bf(f.y - bf2f(h.y));
    h.z = f2bf(f.z); l.z = f2bf(f.z - bf2f(h.z));
    h.w = f2bf(f.w); l.w = f2bf(f.w - bf2f(h.w));
    ((ushort4*)oh)[g] = h;
    ((ushort4*)ol)[g] = l;
}

// ---------------- MFMA GEMM (unchanged, verified) ----------------
__global__ __launch_bounds__(256) void gemm_mfma(const ushort* __restrict__ Ah,
                                                 const ushort* __restrict__ Al,
                                                 const ushort* __restrict__ Wh,
                                                 const ushort* __restrict__ Wl,
                                                 const float* __restrict__ bih,
                                                 const float* __restrict__ bhh,
                                                 float* __restrict__ out, int K)
{
    __shared__ ushort lds[2][128 * 72];
    const int tid = threadIdx.x;
    const int w = tid >> 6, ln = tid & 63;
    const int m0 = blockIdx.y * 128, n0 = blockIdx.x * 128;
    const int arow = (w >> 1) * 64, bcol = (w & 1) * 64;
    const int lm = ln & 15, lk = (ln >> 4) * 8;
    const int sr = tid >> 3, sc = (tid & 7) * 8;

    f32x4 acc[4][4] = {};

#pragma unroll
    for (int s = 0; s < 3; ++s) {
        const ushort* Asrc = (s < 2) ? Ah : Al;
        const ushort* Bsrc = (s == 1) ? Wl : Wh;
        for (int k0 = 0; k0 < K; k0 += 64) {
            __syncthreads();
#pragma unroll
            for (int i = 0; i < 4; ++i) {
                int r = sr + 32 * i;
                *(uint4*)&lds[0][r * 72 + sc] =
                    *(const uint4*)(Asrc + (size_t)(m0 + r) * K + k0 + sc);
                *(uint4*)&lds[1][r * 72 + sc] =
                    *(const uint4*)(Bsrc + (size_t)(n0 + r) * K + k0 + sc);
            }
            __syncthreads();
#pragma unroll
            for (int ks = 0; ks < 2; ++ks) {
                bf16x8 af[4], bf[4];
#pragma unroll
                for (int i = 0; i < 4; ++i)
                    af[i] = *(const bf16x8*)&lds[0][(arow + i * 16 + lm) * 72 + ks * 32 + lk];
#pragma unroll
                for (int j = 0; j < 4; ++j)
                    bf[j] = *(const bf16x8*)&lds[1][(bcol + j * 16 + lm) * 72 + ks * 32 + lk];
#pragma unroll
                for (int i = 0; i < 4; ++i)
#pragma unroll
                    for (int j = 0; j < 4; ++j)
                        acc[i][j] = __builtin_amdgcn_mfma_f32_16x16x32_bf16(
                            af[i], bf[j], acc[i][j], 0, 0, 0);
            }
        }
    }

#pragma unroll
    for (int j = 0; j < 4; ++j) {
        const int n = n0 + bcol + j * 16 + lm;
        const float bsum = bih[n] + bhh[n];
#pragma unroll
        for (int i = 0; i < 4; ++i) {
            const int mrow = m0 + arow + i * 16 + (ln >> 4) * 4;
#pragma unroll
            for (int r = 0; r < 4; ++r) {
                const int m = mrow + r;
                const int bb = m >> 8, tt = m & 255;
                out[(size_t)(tt * 16 + bb) * GG + n] = acc[i][j][r] + bsum;
            }
        }
    }
}

__device__ __forceinline__ float sigf(float x) { return 1.0f / (1.0f + expf(-x)); }

// ---------------- paired-layer scan with data-embedded sync -------------------
__global__ __launch_bounds__(512, 1) void scan_pair(
    const float* __restrict__ WhhE, const float* __restrict__ WhhO,
    const float* __restrict__ WihO, const float* __restrict__ xg,
    ushort* __restrict__ hseq_hi, ushort* __restrict__ hseq_lo,
    unsigned* __restrict__ hEbuf, unsigned* __restrict__ hObuf,
    const float* __restrict__ bihO, const float* __restrict__ bhhO,
    unsigned* __restrict__ prog, unsigned base)
{
    extern __shared__ float smem[];
    char* smb = (char*)smem;
    const int tid  = threadIdx.x;
    const int wgid = blockIdx.x;
    const int half = wgid >> 7, lwg = wgid & 127;
    const int j0 = lwg << 3;
    const int w = tid >> 6, ln = tid & 63;
    const int m = ln & 15, kq = ln >> 4;
    const int t_w = w & 1, s_w = w >> 1;

    unsigned* myH = half ? hObuf : hEbuf;

    // ---- W_hh fragments (step-invariant)
    bf16x8 wf_hi[8], wf_lo[8];
    {
        const int r = t_w * 16 + m;
        const int grow = ((r >> 3) << 10) + j0 + (r & 7);
        const float* wrow = (half ? WhhO : WhhE) + (size_t)grow * 1024 + (s_w << 8) + (kq << 3);
#pragma unroll
        for (int s = 0; s < 8; ++s) {
            float4 f0 = *(const float4*)(wrow + s * 32);
            float4 f1 = *(const float4*)(wrow + s * 32 + 4);
            float fv[8] = {f0.x, f0.y, f0.z, f0.w, f1.x, f1.y, f1.z, f1.w};
            bf16x8 h8, l8;
#pragma unroll
            for (int i = 0; i < 8; ++i) {
                unsigned short hb = f2bf(fv[i]);
                h8[i] = (short)hb;
                l8[i] = (short)f2bf(fv[i] - bf2f(hb));
            }
            wf_hi[s] = h8; wf_lo[s] = l8;
        }
    }
    // ---- W_ih fragments (odd half only)
    bf16x8 uf_hi[8], uf_lo[8];
    if (half) {
        const int r = t_w * 16 + m;
        const int grow = ((r >> 3) << 10) + j0 + (r & 7);
        const float* wrow = WihO + (size_t)grow * 1024 + (s_w << 8) + (kq << 3);
#pragma unroll
        for (int s = 0; s < 8; ++s) {
            float4 f0 = *(const float4*)(wrow + s * 32);
            float4 f1 = *(const float4*)(wrow + s * 32 + 4);
            float fv[8] = {f0.x, f0.y, f0.z, f0.w, f1.x, f1.y, f1.z, f1.w};
            bf16x8 h8, l8;
#pragma unroll
            for (int i = 0; i < 8; ++i) {
                unsigned short hb = f2bf(fv[i]);
                h8[i] = (short)hb;
                l8[i] = (short)f2bf(fv[i] - bf2f(hb));
            }
            uf_hi[s] = h8; uf_lo[s] = l8;
        }
    }

    const int bidx = ln >> 4, jj = ln & 15;
    const int kkloc = jj >> 1, sub = (jj & 1) * 8;
    const int q = tid >> 4, bg = tid & 15;     // gate lanes (tid<64)

    float cs0 = 0.f, cs1 = 0.f;
    float2 gin[4] = {};
    if (tid < 64) {
        if (half) {
#pragma unroll
            for (int g = 0; g < 4; ++g) {
                const int c0 = g * 1024 + j0 + 2 * q;
                gin[g] = make_float2(bihO[c0] + bhhO[c0], bihO[c0 + 1] + bhhO[c0 + 1]);
            }
        } else {
#pragma unroll
            for (int g = 0; g < 4; ++g)
                gin[g] = *(const float2*)(xg + (size_t)bg * GG + g * 1024 + j0 + 2 * q);
        }
    }

    for (int t = 0; t < TT; ++t) {
        const unsigned gstep = base + (unsigned)t;
        const unsigned eE = (gstep >> 2) & 1u;              // partner tag (odd reads even h(t))
        const unsigned eR = ((gstep - 1u) >> 2) & 1u;       // own h(t-1) tag (t>0)

        // ---- 1. spin-load sources until genbits match (data IS the flag)
        uint4 vE[2][4], vR[2][4];
        if (half || t > 0) {
            const uint4* pEb = (const uint4*)(hEbuf + ((gstep & 3u) << 14));
            const uint4* pRb = (const uint4*)(myH + (((gstep - 1u) & 3u) << 14));
            while (true) {
                if (half) {
#pragma unroll
                    for (int cc = 0; cc < 2; ++cc) {
                        const uint4* p = pEb + ((w << 1) + cc) * 256 + ln;
                        asm volatile(
                            "global_load_dwordx4 %0, %4, off sc0 sc1\n\t"
                            "global_load_dwordx4 %1, %4, off offset:1024 sc0 sc1\n\t"
                            "global_load_dwordx4 %2, %4, off offset:2048 sc0 sc1\n\t"
                            "global_load_dwordx4 %3, %4, off offset:3072 sc0 sc1"
                            : "=&v"(vE[cc][0]), "=&v"(vE[cc][1]), "=&v"(vE[cc][2]), "=&v"(vE[cc][3])
                            : "v"(p) : "memory");
                    }
                }
                if (t > 0) {
#pragma unroll
                    for (int cc = 0; cc < 2; ++cc) {
                        const uint4* p = pRb + ((w << 1) + cc) * 256 + ln;
                        asm volatile(
                            "global_load_dwordx4 %0, %4, off sc0 sc1\n\t"
                            "global_load_dwordx4 %1, %4, off offset:1024 sc0 sc1\n\t"
                            "global_load_dwordx4 %2, %4, off offset:2048 sc0 sc1\n\t"
                            "global_load_dwordx4 %3, %4, off offset:3072 sc0 sc1"
                            : "=&v"(vR[cc][0]), "=&v"(vR[cc][1]), "=&v"(vR[cc][2]), "=&v"(vR[cc][3])
                            : "v"(p) : "memory");
                    }
                }
                asm volatile("s_waitcnt vmcnt(0)" ::: "memory");
                __builtin_amdgcn_sched_barrier(0);
                unsigned bad = 0u;
                if (half) {
#pragma unroll
                    for (int cc = 0; cc < 2; ++cc)
#pragma unroll
                        for (int i = 0; i < 4; ++i) {
                            uint4 v = vE[cc][i];
                            bad |= ((v.x >> 16) ^ eE) & 1u; bad |= ((v.y >> 16) ^ eE) & 1u;
                            bad |= ((v.z >> 16) ^ eE) & 1u; bad |= ((v.w >> 16) ^ eE) & 1u;
                        }
                }
                if (t > 0) {
#pragma unroll
                    for (int cc = 0; cc < 2; ++cc)
#pragma unroll
                        for (int i = 0; i < 4; ++i) {
                            uint4 v = vR[cc][i];
                            bad |= ((v.x >> 16) ^ eR) & 1u; bad |= ((v.y >> 16) ^ eR) & 1u;
                            bad |= ((v.z >> 16) ^ eR) & 1u; bad |= ((v.w >> 16) ^ eR) & 1u;
                        }
                }
                if (__all(bad == 0u)) break;
                __builtin_amdgcn_s_sleep(1);
            }
        }

        // ---- 2. stage into LDS (wave-private regions)
        if (half) {
#pragma unroll
            for (int cc = 0; cc < 2; ++cc) {
                const int kk = ((w << 1) + cc) * 8 + kkloc;          // 0..127
#pragma unroll
                for (int i = 0; i < 4; ++i) {
                    const int b = (i << 2) + bidx;
                    uint4 pv = vE[cc][i];
                    uint2 uh = {(pv.x & 0xFFFFu) | (pv.y << 16),
                                (pv.z & 0xFFFFu) | (pv.w << 16)};
                    uint2 ul = {(pv.x >> 16) | (pv.y & 0xFFFF0000u),
                                (pv.z >> 16) | (pv.w & 0xFFFF0000u)};
                    char* bp = smb + kk * 272 + b * 16 + sub;
                    *(uint2*)bp = uh;
                    *(uint2*)(bp + BLO_B) = ul;
                }
            }
        }
        if (t > 0) {
#pragma unroll
            for (int cc = 0; cc < 2; ++cc) {
                const int kk = 128 + ((w << 1) + cc) * 8 + kkloc;    // 128..255
#pragma unroll
                for (int i = 0; i < 4; ++i) {
                    const int b = (i << 2) + bidx;
                    uint4 pv = vR[cc][i];
                    uint2 uh = {(pv.x & 0xFFFFu) | (pv.y << 16),
                                (pv.z & 0xFFFFu) | (pv.w << 16)};
                    uint2 ul = {(pv.x >> 16) | (pv.y & 0xFFFF0000u),
                                (pv.z >> 16) | (pv.w & 0xFFFF0000u)};
                    char* bp = smb + kk * 272 + b * 16 + sub;
                    *(uint2*)bp = uh;
                    *(uint2*)(bp + BLO_B) = ul;
                }
            }
        }
        __syncthreads();

        // odd: publish consumption progress (even h(t) fully consumed into regs/LDS)
        if (half && tid == 0)
            __hip_atomic_store(prog + (lwg << 4), gstep + 1u,
                               __ATOMIC_RELAXED, __HIP_MEMORY_SCOPE_AGENT);

        // ---- 3. MFMAs
        f32x4 aA = {0.f, 0.f, 0.f, 0.f};
        f32x4 aB = {0.f, 0.f, 0.f, 0.f};
        f32x4 aC = {0.f, 0.f, 0.f, 0.f};
        const char* hbx = smb + ((s_w << 5) + kq) * 272 + m * 16;
        const char* hbr = hbx + 128 * 272;
        if (half) {
#pragma unroll
            for (int s = 0; s < 8; ++s) {
                bf16x8 bh = *(const bf16x8*)(hbx + s * 1088);
                bf16x8 bl = *(const bf16x8*)(hbx + BLO_B + s * 1088);
                aA = __builtin_amdgcn_mfma_f32_16x16x32_bf16(uf_hi[s], bh, aA, 0, 0, 0);
                aB = __builtin_amdgcn_mfma_f32_16x16x32_bf16(uf_hi[s], bl, aB, 0, 0, 0);
                aC = __builtin_amdgcn_mfma_f32_16x16x32_bf16(uf_lo[s], bh, aC, 0, 0, 0);
            }
        }
        if (t > 0) {
#pragma unroll
            for (int s = 0; s < 8; ++s) {
                bf16x8 bh = *(const bf16x8*)(hbr + s * 1088);
                bf16x8 bl = *(const bf16x8*)(hbr + BLO_B + s * 1088);
                aA = __builtin_amdgcn_mfma_f32_16x16x32_bf16(wf_hi[s], bh, aA, 0, 0, 0);
                aB = __builtin_amdgcn_mfma_f32_16x16x32_bf16(wf_hi[s], bl, aB, 0, 0, 0);
                aC = __builtin_amdgcn_mfma_f32_16x16x32_bf16(wf_lo[s], bh, aC, 0, 0, 0);
            }
        }
        f32x4 asum = aA + aB;
        asum = asum + aC;

        // ---- 4. partials
#pragma unroll
        for (int r = 0; r < 4; ++r)
            smem[PART_F + w * 272 + ((kq << 2) + r) * 17 + m] = asum[r];
        __syncthreads();

        // ---- 5. even back-pressure: odd must have consumed even h(gstep-4)
        if (!half && t >= 4 && tid == 0) {
            unsigned* p = prog + (lwg << 4);
            while (__hip_atomic_load(p, __ATOMIC_RELAXED, __HIP_MEMORY_SCOPE_AGENT) < gstep - 3u)
                __builtin_amdgcn_s_sleep(1);
        }

        // ---- 6. gates (wave 0): reduce, activations, tagged h store
        if (tid < 64) {
#pragma unroll
            for (int cc = 0; cc < 2; ++cc) {
                const int ch = 2 * q + cc;
                float iv = cc ? gin[0].y : gin[0].x;
                float fv = cc ? gin[1].y : gin[1].x;
                float gv = cc ? gin[2].y : gin[2].x;
                float ov = cc ? gin[3].y : gin[3].x;
#pragma unroll
                for (int s = 0; s < 4; ++s) {
                    iv += smem[PART_F + (2 * s    ) * 272 + (ch    ) * 17 + bg];
                    fv += smem[PART_F + (2 * s    ) * 272 + (ch + 8) * 17 + bg];
                    gv += smem[PART_F + (2 * s + 1) * 272 + (ch    ) * 17 + bg];
                    ov += smem[PART_F + (2 * s + 1) * 272 + (ch + 8) * 17 + bg];
                }
                float& cs = cc ? cs1 : cs0;
                cs = sigf(fv) * cs + sigf(iv) * tanhf(gv);
                float hval = sigf(ov) * tanhf(cs);
                unsigned short hh_ = f2bf(hval);
                unsigned short hl_ = f2bf(hval - bf2f(hh_));
                if (half) {   // exact hseq for next-phase GEMM / FC head
                    const int col = j0 + ch;
                    size_t idx = (size_t)(bg * TT + t) * HH + col;
                    hseq_hi[idx] = hh_;
                    hseq_lo[idx] = hl_;
                }
                // tag: lo LSB := generation bit
                unsigned short hlt = (unsigned short)((hl_ & 0xFFFEu) | ((gstep >> 2) & 1u));
                unsigned pk = (unsigned)hh_ | ((unsigned)hlt << 16);
                const int col = j0 + ch;
                unsigned* hdst = myH + ((gstep & 3u) << 14) +
                                 ((col >> 6) << 10) + (bg << 6) + (col & 63);
                asm volatile("global_store_dword %0, %1, off sc0 sc1"
                             :: "v"(hdst), "v"(pk) : "memory");
            }
            // even: prefetch next xg (off critical path)
            if (!half && t + 1 < TT) {
#pragma unroll
                for (int g = 0; g < 4; ++g)
                    gin[g] = *(const float2*)(xg + (size_t)((t + 1) * 16 + bg) * GG +
                                              g * 1024 + j0 + 2 * q);
            }
        }
    }
}

// ---------------- FC head ----------------
__global__ void fc_relu_split(const ushort* __restrict__ ih, const ushort* __restrict__ il,
                              const float* __restrict__ w, const float* __restrict__ b,
                              float* __restrict__ out, int N, int K)
{
    int g = blockIdx.x * blockDim.x + threadIdx.x;
    if (g >= BB * N) return;
    int bi = g / N, n = g - bi * N;
    const ushort* ph = ih + (size_t)(bi * 256 + 255) * 1024;
    const ushort* pl = il + (size_t)(bi * 256 + 255) * 1024;
    const float* wp = w + (size_t)n * K;
    float s = 0.f;
    for (int k = 0; k < K; k += 4) {
        ushort4 uh = *(const ushort4*)(ph + k);
        ushort4 ul = *(const ushort4*)(pl + k);
        float4 qv = *(const float4*)(wp + k);
        s += (bf2f(uh.x) + bf2f(ul.x)) * qv.x + (bf2f(uh.y) + bf2f(ul.y)) * qv.y +
             (bf2f(uh.z) + bf2f(ul.z)) * qv.z + (bf2f(uh.w) + bf2f(ul.w)) * qv.w;
    }
    s += b[n];
    out[g] = fmaxf(s, 0.f);
}

__global__ void fc_relu(const float* __restrict__ in, const float* __restrict__ w,
                        const float* __restrict__ b, float* __restrict__ out,
                        int N, int K, int do_relu)
{
    int g = blockIdx.x * blockDim.x + threadIdx.x;
    if (g >= BB * N) return;
    int bi = g / N, n = g - bi * N;
    const float* ip = in + (size_t)bi * K;
    const float* wp = w + (size_t)n * K;
    float s = 0.f;
    for (int k = 0; k < K; k += 4) {
        float4 a = *(const float4*)(ip + k);
        float4 qv = *(const float4*)(wp + k);
        s += a.x * qv.x + a.y * qv.y + a.z * qv.z + a.w * qv.w;
    }
    s += b[n];
    if (do_relu) s = fmaxf(s, 0.f);
    out[g] = s;
}

// ---------------- launch ----------------
extern "C" void kernel_launch(void* const* d_in, const int* in_sizes, int n_in,
                              void* d_out, int out_size, void* d_ws, size_t ws_size,
                              hipStream_t stream)
{
    const float* x    = (const float*)d_in[0];
    const float* Wih0 = (const float*)d_in[1];
    const float* WihR = (const float*)d_in[2];
    const float* Whh  = (const float*)d_in[3];
    const float* bih  = (const float*)d_in[4];
    const float* bhh  = (const float*)d_in[5];
    const float* fc1w = (const float*)d_in[6];
    const float* fc1b = (const float*)d_in[7];
    const float* fc2w = (const float*)d_in[8];
    const float* fc2b = (const float*)d_in[9];
    const float* fc3w = (const float*)d_in[10];
    const float* fc3b = (const float*)d_in[11];
    float* out = (float*)d_out;
    char* ws = (char*)d_ws;

    float* xg      = (float*)(ws + XG_OFF);
    ushort* reg0   = (ushort*)(ws + REG0_OFF);
    ushort* hs_hi  = (ushort*)(ws + REG1_OFF);
    ushort* hs_lo  = hs_hi + 4194304;
    unsigned* hE   = (unsigned*)(ws + HE_OFF);
    unsigned* hO   = (unsigned*)(ws + HO_OFF);
    float* fc1o    = (float*)(ws + FC1_OFF);
    float* fc2o    = (float*)(ws + FC2_OFF);
    unsigned* prog = (unsigned*)(ws + PRG_OFF);

    (void)hipFuncSetAttribute((const void*)scan_pair,
                              hipFuncAttributeMaxDynamicSharedMemorySize, SMEM_BYTES);
    // h slots -> 0xFF (genbit=1, mismatches first-generation expectation 0);
    // prog -> 0 (must reset every launch or graph replay deadlocks)
    (void)hipMemsetAsync(ws + HE_OFF, 0xFF, 524288, stream);
    (void)hipMemsetAsync(ws + PRG_OFF, 0, 8192, stream);

    // phase-0 conversions: xcv (8MB) + W_ih(0) split (8MB) into REG0
    ushort* xcv_hi = reg0;
    ushort* xcv_lo = reg0 + 2097152;
    ushort* w0h    = reg0 + 4194304;
    ushort* w0l    = reg0 + 6291456;
    conv_split<<<2048, 256, 0, stream>>>(x, xcv_hi, xcv_lo, (BB * TT * IN0) / 4);
    conv_split<<<2048, 256, 0, stream>>>(Wih0, w0h, w0l, (GG * IN0) / 4);
    gemm_mfma<<<dim3(32, 32), 256, 0, stream>>>(xcv_hi, xcv_lo, w0h, w0l,
                                                bih, bhh, xg, IN0);

    for (int p = 0; p < 4; ++p) {
        if (p > 0) {
            const float* Wl = WihR + (size_t)(2 * p - 1) * GG * HH;
            conv_split<<<4096, 256, 0, stream>>>(Wl, reg0, reg0 + 4194304, (GG * HH) / 4);
            gemm_mfma<<<dim3(32, 32), 256, 0, stream>>>(
                hs_hi, hs_lo, reg0, reg0 + 4194304,
                bih + (size_t)(2 * p) * GG, bhh + (size_t)(2 * p) * GG, xg, HH);
        }
        const float* whhE = Whh + (size_t)(2 * p) * GG * HH;
        const float* whhO = Whh + (size_t)(2 * p + 1) * GG * HH;
        const float* wihO = WihR + (size_t)(2 * p) * GG * HH;
        const float* bO   = bih + (size_t)(2 * p + 1) * GG;
        const float* bhO  = bhh + (size_t)(2 * p + 1) * GG;
        unsigned base = 256u * (unsigned)p;
        void* args[12] = {(void*)&whhE, (void*)&whhO, (void*)&wihO, (void*)&xg,
                          (void*)&hs_hi, (void*)&hs_lo, (void*)&hE, (void*)&hO,
                          (void*)&bO, (void*)&bhO, (void*)&prog, (void*)&base};
        hipError_t e = hipLaunchCooperativeKernel((void*)scan_pair, dim3(256), dim3(512),
                                                  args, SMEM_BYTES, stream);
        if (e != hipSuccess) {
            scan_pair<<<dim3(256), dim3(512), SMEM_BYTES, stream>>>(
                whhE, whhO, wihO, xg, hs_hi, hs_lo, hE, hO, bO, bhO, prog, base);
        }
    }

    // FC head: hseq(7) in REG1
    fc_relu_split<<<32, 256, 0, stream>>>(hs_hi, hs_lo, fc1w, fc1b, fc1o, 512, 1024);
    fc_relu<<<16, 256, 0, stream>>>(fc1o, fc2w, fc2b, fc2o, 256, 512, 1);
    fc_relu<<<1, 16, 0, stream>>>(fc2o, fc3w, fc3b, out, 1, 256, 0);
}